// Round 1
// baseline (701.793 us; speedup 1.0000x reference)
//
#include <hip/hip_runtime.h>

// ---- problem constants ----
#define NB    32
#define CI    256
#define CO    256
#define HH    56
#define WW    56
#define SPAT  3136        // 56*56
#define KTOT  2304        // CI*9
#define RK    48          // R*K = 16*3
#define WELEM 589824      // CO*KTOT = 768*768
#define HP    58          // padded H/W

typedef __attribute__((ext_vector_type(8))) short short8;
typedef __attribute__((ext_vector_type(4))) float f32x4;

static __device__ __forceinline__ unsigned short f2bf(float f) {
    union { float f; unsigned int u; } v; v.f = f;
    unsigned int u = v.u;
    return (unsigned short)((u + 0x7fffu + ((u >> 16) & 1u)) >> 16);
}

// ---------------------------------------------------------------------------
// Kernel 1: per-sample weight synthesis.
// wsW[b][f] = bf16( W0[f] + 2 * sum_t alpha[b][t] * (B_t A_t)[f] ),
// f = i*768 + j  ==  flat [o][ci][k1][k2] index (reshape identity).
// Grid: 144 blocks (12x12 tiles of 64x64), 256 threads.
// ---------------------------------------------------------------------------
__global__ __launch_bounds__(256) void synth_weights(
    const float* __restrict__ alphas,   // [32][8]
    const float* __restrict__ w0,       // [WELEM]
    const float* __restrict__ loraA,    // [8][48][768]
    const float* __restrict__ loraB,    // [8][768][48]
    unsigned short* __restrict__ wsW)   // [32][WELEM] bf16
{
    __shared__ float Bs[64][RK];     // 12 KB
    __shared__ float As[RK][64];     // 12 KB
    __shared__ float sAl[NB][8];     // 1 KB

    const int i0 = (blockIdx.x / 12) * 64;
    const int j0 = (blockIdx.x % 12) * 64;
    const int tid = threadIdx.x;
    sAl[tid >> 3][tid & 7] = alphas[tid];   // 256 threads == 256 alphas

    const int tr = tid >> 4;   // 0..15
    const int tc = tid & 15;   // 0..15

    float mt[8][16];
    #pragma unroll
    for (int t = 0; t < 8; ++t) {
        __syncthreads();
        for (int e = tid; e < 64 * RK; e += 256) {
            int ii = e / RK, rr = e % RK;
            Bs[ii][rr] = loraB[(size_t)(t * 768 + i0 + ii) * RK + rr];
        }
        for (int e = tid; e < RK * 64; e += 256) {
            int rr = e / 64, jj = e % 64;
            As[rr][jj] = loraA[(size_t)(t * RK + rr) * 768 + j0 + jj];
        }
        __syncthreads();
        float acc[16];
        #pragma unroll
        for (int e = 0; e < 16; ++e) acc[e] = 0.f;
        for (int r = 0; r < RK; ++r) {
            float bv[4], av[4];
            #pragma unroll
            for (int d = 0; d < 4; ++d) { bv[d] = Bs[tr * 4 + d][r]; av[d] = As[r][tc * 4 + d]; }
            #pragma unroll
            for (int di = 0; di < 4; ++di)
                #pragma unroll
                for (int dj = 0; dj < 4; ++dj)
                    acc[di * 4 + dj] += bv[di] * av[dj];
        }
        #pragma unroll
        for (int e = 0; e < 16; ++e) mt[t][e] = acc[e];
    }

    float w0v[16];
    #pragma unroll
    for (int di = 0; di < 4; ++di)
        #pragma unroll
        for (int dj = 0; dj < 4; ++dj)
            w0v[di * 4 + dj] = w0[(size_t)(i0 + tr * 4 + di) * 768 + j0 + tc * 4 + dj];

    for (int b = 0; b < NB; ++b) {
        #pragma unroll
        for (int di = 0; di < 4; ++di) {
            #pragma unroll
            for (int dj = 0; dj < 4; ++dj) {
                float v = 0.f;
                #pragma unroll
                for (int t = 0; t < 8; ++t) v += sAl[b][t] * mt[t][di * 4 + dj];
                float o = w0v[di * 4 + dj] + 2.0f * v;
                wsW[(size_t)b * WELEM + (size_t)(i0 + tr * 4 + di) * 768 + j0 + tc * 4 + dj] = f2bf(o);
            }
        }
    }
}

// ---------------------------------------------------------------------------
// Kernel 2: zero-halo-padded bf16 copy of x:  xp[b][c][58][58]
// ---------------------------------------------------------------------------
__global__ __launch_bounds__(256) void pad_x(
    const float* __restrict__ x, unsigned short* __restrict__ xp)
{
    int idx = blockIdx.x * 256 + threadIdx.x;   // over NB*CI*58*58 = 27,557,888
    int xx = idx % HP;
    int t1 = idx / HP;
    int yy = t1 % HP;
    int bc = t1 / HP;
    float v = 0.f;
    if (xx >= 1 && xx <= WW && yy >= 1 && yy <= HH)
        v = x[((size_t)bc * HH + (yy - 1)) * WW + (xx - 1)];
    xp[idx] = f2bf(v);
}

// ---------------------------------------------------------------------------
// Kernel 3: implicit-GEMM conv via MFMA.
// Tile: BM=128 (o) x BN=112 (spatial = 2 full image rows), BK=32, 72 K-steps.
// 4 waves; wave w owns o-rows [w*32, w*32+32): 2 x 7 fragments of 16x16.
// Grid: (28 nTiles, 2 mTiles, 32 samples).
// ---------------------------------------------------------------------------
template <bool PAD>
__global__ __launch_bounds__(256) void conv_mfma(
    const float* __restrict__ x,            // unpadded fp32 (fallback path)
    const unsigned short* __restrict__ xp,  // padded bf16 (fast path)
    const unsigned short* __restrict__ wsW, // [32][256][2304] bf16
    float* __restrict__ out)                // [32][256][3136] fp32
{
    __shared__ unsigned short Asm[128][40];  // [o][kk], pitch 40 (2-way bank alias)
    __shared__ unsigned short Bsm[112][40];  // [n][kk]

    const int nT = blockIdx.x;      // 0..27
    const int mT = blockIdx.y;      // 0..1
    const int b  = blockIdx.z;      // 0..31
    const int tid  = threadIdx.x;
    const int wv   = tid >> 6;
    const int lane = tid & 63;
    const int y0   = nT * 2;

    f32x4 acc[2][7];
    #pragma unroll
    for (int mf = 0; mf < 2; ++mf)
        #pragma unroll
        for (int nf = 0; nf < 7; ++nf)
            acc[mf][nf] = (f32x4){0.f, 0.f, 0.f, 0.f};

    const unsigned short* wBase =
        wsW + (size_t)b * WELEM + (size_t)(mT * 128) * KTOT;

    // A-staging: thread -> (row=tid>>1, 16 bf16 at col (tid&1)*16)
    const int arow = tid >> 1;
    const int acol = (tid & 1) * 16;
    // B-staging: thread -> (kk=tid>>3, 14 spatial at n0=(tid&7)*14)
    const int bkk = tid >> 3;
    const int bg  = tid & 7;

    for (int kt = 0; kt < 72; ++kt) {
        const int k0 = kt * 32;
        // ---- stage A (weights), coalesced 16B loads ----
        {
            const unsigned short* src = wBase + (size_t)arow * KTOT + k0 + acol;
            uint4 v0 = *(const uint4*)(src);
            uint4 v1 = *(const uint4*)(src + 8);
            *(uint4*)&Asm[arow][acol]     = v0;
            *(uint4*)&Asm[arow][acol + 8] = v1;
        }
        // ---- stage B (im2col of x) ----
        {
            const int kidx = k0 + bkk;
            const int ci = kidx / 9;
            const int p  = kidx - ci * 9;
            const int dy = p / 3;          // 0..2
            const int dx = p - dy * 3;     // 0..2
            const int n0 = bg * 14;
            if (PAD) {
                const int yy = y0 + (bg >> 2) + dy;             // into padded rows
                const int xb = (bg & 3) * 14 + dx;
                const unsigned short* src =
                    xp + ((size_t)(b * CI + ci) * HP + yy) * HP + xb;
                #pragma unroll
                for (int e = 0; e < 14; ++e) Bsm[n0 + e][bkk] = src[e];
            } else {
                const int yb = y0 + (bg >> 2) + dy - 1;
                const bool yok = (yb >= 0) && (yb < HH);
                const float* src = x + ((size_t)(b * CI + ci) * HH + yb) * WW;
                #pragma unroll
                for (int e = 0; e < 14; ++e) {
                    int xc = (bg & 3) * 14 + e + dx - 1;
                    float v = (yok && xc >= 0 && xc < WW) ? src[xc] : 0.f;
                    Bsm[n0 + e][bkk] = f2bf(v);
                }
            }
        }
        __syncthreads();

        // ---- fragments + MFMA ----
        const int rsel = lane & 15;
        const int koff = (lane >> 4) * 8;
        short8 af[2], bfr[7];
        af[0] = *(const short8*)&Asm[wv * 32 + rsel][koff];
        af[1] = *(const short8*)&Asm[wv * 32 + 16 + rsel][koff];
        #pragma unroll
        for (int nf = 0; nf < 7; ++nf)
            bfr[nf] = *(const short8*)&Bsm[nf * 16 + rsel][koff];
        #pragma unroll
        for (int mf = 0; mf < 2; ++mf)
            #pragma unroll
            for (int nf = 0; nf < 7; ++nf)
                acc[mf][nf] = __builtin_amdgcn_mfma_f32_16x16x32_bf16(
                    af[mf], bfr[nf], acc[mf][nf], 0, 0, 0);
        __syncthreads();
    }

    // ---- epilogue: D[row=(l>>4)*4+r][col=l&15] ----
    const int colb = lane & 15;
    const int rowb = (lane >> 4) * 4;
    #pragma unroll
    for (int mf = 0; mf < 2; ++mf) {
        const int o = mT * 128 + wv * 32 + mf * 16 + rowb;
        #pragma unroll
        for (int nf = 0; nf < 7; ++nf) {
            const int s = nT * 112 + nf * 16 + colb;
            float* dst = out + ((size_t)(b * CO + o)) * SPAT + s;
            #pragma unroll
            for (int r = 0; r < 4; ++r)
                dst[(size_t)r * SPAT] = acc[mf][nf][r];
        }
    }
}

// ---------------------------------------------------------------------------
extern "C" void kernel_launch(void* const* d_in, const int* in_sizes, int n_in,
                              void* d_out, int out_size, void* d_ws, size_t ws_size,
                              hipStream_t stream)
{
    const float* x  = (const float*)d_in[0];
    const float* al = (const float*)d_in[1];
    const float* w0 = (const float*)d_in[2];
    const float* lA = (const float*)d_in[3];
    const float* lB = (const float*)d_in[4];
    float* out = (float*)d_out;

    unsigned short* wsW  = (unsigned short*)d_ws;
    const size_t WSW_ELEMS  = (size_t)NB * WELEM;          // 18,874,368
    const size_t XPAD_ELEMS = (size_t)NB * CI * HP * HP;   // 27,557,888
    unsigned short* xpad = wsW + WSW_ELEMS;
    const bool usePad = ws_size >= (WSW_ELEMS + XPAD_ELEMS) * 2u;  // ~92.9 MB

    synth_weights<<<144, 256, 0, stream>>>(al, w0, lA, lB, wsW);
    if (usePad) {
        pad_x<<<(int)(XPAD_ELEMS / 256), 256, 0, stream>>>(x, xpad);
        conv_mfma<true><<<dim3(28, 2, 32), 256, 0, stream>>>(x, xpad, wsW, out);
    } else {
        conv_mfma<false><<<dim3(28, 2, 32), 256, 0, stream>>>(x, xpad, wsW, out);
    }
}

// Round 2
// 440.192 us; speedup vs baseline: 1.5943x; 1.5943x over previous
//
#include <hip/hip_runtime.h>

// ---- problem constants ----
#define NB    32
#define CI    256
#define CO    256
#define HH    56
#define WW    56
#define SPAT  3136        // 56*56
#define KTOT  2304        // CI*9
#define RK    48          // R*K = 16*3
#define WELEM 589824      // CO*KTOT = 768*768
#define MELEM 589824      // per-task M elements
#define HP    58          // padded H/W

typedef __attribute__((ext_vector_type(8))) short short8;
typedef __attribute__((ext_vector_type(4))) float f32x4;

static __device__ __forceinline__ unsigned short f2bf(float f) {
    union { float f; unsigned int u; } v; v.f = f;
    unsigned int u = v.u;
    return (unsigned short)((u + 0x7fffu + ((u >> 16) & 1u)) >> 16);
}
static __device__ __forceinline__ unsigned int pack2bf(float lo, float hi) {
    return (unsigned int)f2bf(lo) | ((unsigned int)f2bf(hi) << 16);
}

// ---------------------------------------------------------------------------
// Kernel S1: Mstack[t][i][j] = (B_t A_t)[i][j], fp32.
// Grid: dim3(144, 8) -> 12x12 tiles of 64x64 per task. 256 threads.
// ---------------------------------------------------------------------------
__global__ __launch_bounds__(256) void mstack_gemm(
    const float* __restrict__ loraA,    // [8][48][768]
    const float* __restrict__ loraB,    // [8][768][48]
    float* __restrict__ M)              // [8][768][768]
{
    __shared__ float BsT[RK][65];   // [r][i], pitch 65 -> conflict-free col reads
    __shared__ float As[RK][64];    // [r][j]

    const int t  = blockIdx.y;
    const int i0 = (blockIdx.x / 12) * 64;
    const int j0 = (blockIdx.x % 12) * 64;
    const int tid = threadIdx.x;

    for (int e = tid; e < 64 * RK; e += 256) {      // coalesced rows of loraB
        int ii = e / RK, rr = e % RK;
        BsT[rr][ii] = loraB[(size_t)(t * 768 + i0 + ii) * RK + rr];
    }
    for (int e = tid; e < RK * 64; e += 256) {
        int rr = e / 64, jj = e % 64;
        As[rr][jj] = loraA[(size_t)(t * RK + rr) * 768 + j0 + jj];
    }
    __syncthreads();

    const int tr = tid >> 4, tc = tid & 15;
    float acc[16];
    #pragma unroll
    for (int e = 0; e < 16; ++e) acc[e] = 0.f;

    for (int r = 0; r < RK; ++r) {
        float bv[4], av[4];
        #pragma unroll
        for (int d = 0; d < 4; ++d) { bv[d] = BsT[r][tr * 4 + d]; av[d] = As[r][tc * 4 + d]; }
        #pragma unroll
        for (int di = 0; di < 4; ++di)
            #pragma unroll
            for (int dj = 0; dj < 4; ++dj)
                acc[di * 4 + dj] += bv[di] * av[dj];
    }

    #pragma unroll
    for (int di = 0; di < 4; ++di) {
        float* dst = M + (size_t)t * MELEM + (size_t)(i0 + tr * 4 + di) * 768 + j0 + tc * 4;
        *(f32x4*)dst = (f32x4){acc[di * 4 + 0], acc[di * 4 + 1], acc[di * 4 + 2], acc[di * 4 + 3]};
    }
}

// ---------------------------------------------------------------------------
// Kernel S2: wsW[b][f] = bf16(W0[f] + sum_t (2*alpha[b][t]) * M[t][f]).
// Thread owns one 8-float granule; loads W0+M once, loops 8 samples.
// Grid: dim3(288, 4) -> 73728 granules x 4 b-groups of 8. 256 threads.
// ---------------------------------------------------------------------------
__global__ __launch_bounds__(256) void combine_weights(
    const float* __restrict__ alphas,   // [32][8]
    const float* __restrict__ w0,       // [WELEM]
    const float* __restrict__ M,        // [8][WELEM]
    unsigned short* __restrict__ wsW)   // [32][WELEM]
{
    __shared__ float sAl[8][8];         // [bLocal][t], pre-scaled by 2
    const int tid = threadIdx.x;
    const int b0  = blockIdx.y * 8;
    if (tid < 64) sAl[tid >> 3][tid & 7] = alphas[(b0 + (tid >> 3)) * 8 + (tid & 7)] * 2.0f;
    __syncthreads();

    const size_t g  = (size_t)blockIdx.x * 256 + tid;   // granule index
    const size_t f0 = g * 8;

    f32x4 w0a = *(const f32x4*)&w0[f0];
    f32x4 w0b = *(const f32x4*)&w0[f0 + 4];
    f32x4 Ma[8], Mb[8];
    #pragma unroll
    for (int t = 0; t < 8; ++t) {
        Ma[t] = *(const f32x4*)&M[(size_t)t * MELEM + f0];
        Mb[t] = *(const f32x4*)&M[(size_t)t * MELEM + f0 + 4];
    }

    for (int bl = 0; bl < 8; ++bl) {
        f32x4 va = w0a, vb = w0b;
        #pragma unroll
        for (int t = 0; t < 8; ++t) {
            float a = sAl[bl][t];
            va += a * Ma[t];
            vb += a * Mb[t];
        }
        uint4 o;
        o.x = pack2bf(va[0], va[1]);
        o.y = pack2bf(va[2], va[3]);
        o.z = pack2bf(vb[0], vb[1]);
        o.w = pack2bf(vb[2], vb[3]);
        *(uint4*)&wsW[(size_t)(b0 + bl) * WELEM + f0] = o;
    }
}

// ---------------------------------------------------------------------------
// Fallback synthesis (only if ws too small for Mstack) — old monolithic path.
// ---------------------------------------------------------------------------
__global__ __launch_bounds__(256) void synth_weights_fb(
    const float* __restrict__ alphas, const float* __restrict__ w0,
    const float* __restrict__ loraA, const float* __restrict__ loraB,
    unsigned short* __restrict__ wsW)
{
    __shared__ float Bs[64][RK];
    __shared__ float As[RK][64];
    __shared__ float sAl[NB][8];
    const int i0 = (blockIdx.x / 12) * 64;
    const int j0 = (blockIdx.x % 12) * 64;
    const int tid = threadIdx.x;
    sAl[tid >> 3][tid & 7] = alphas[tid];
    const int tr = tid >> 4, tc = tid & 15;
    float mt[8][16];
    #pragma unroll
    for (int t = 0; t < 8; ++t) {
        __syncthreads();
        for (int e = tid; e < 64 * RK; e += 256) {
            int ii = e / RK, rr = e % RK;
            Bs[ii][rr] = loraB[(size_t)(t * 768 + i0 + ii) * RK + rr];
        }
        for (int e = tid; e < RK * 64; e += 256) {
            int rr = e / 64, jj = e % 64;
            As[rr][jj] = loraA[(size_t)(t * RK + rr) * 768 + j0 + jj];
        }
        __syncthreads();
        float acc[16];
        #pragma unroll
        for (int e = 0; e < 16; ++e) acc[e] = 0.f;
        for (int r = 0; r < RK; ++r) {
            float bv[4], av[4];
            #pragma unroll
            for (int d = 0; d < 4; ++d) { bv[d] = Bs[tr * 4 + d][r]; av[d] = As[r][tc * 4 + d]; }
            #pragma unroll
            for (int di = 0; di < 4; ++di)
                #pragma unroll
                for (int dj = 0; dj < 4; ++dj)
                    acc[di * 4 + dj] += bv[di] * av[dj];
        }
        #pragma unroll
        for (int e = 0; e < 16; ++e) mt[t][e] = acc[e];
    }
    float w0v[16];
    #pragma unroll
    for (int di = 0; di < 4; ++di)
        #pragma unroll
        for (int dj = 0; dj < 4; ++dj)
            w0v[di * 4 + dj] = w0[(size_t)(i0 + tr * 4 + di) * 768 + j0 + tc * 4 + dj];
    for (int b = 0; b < NB; ++b)
        #pragma unroll
        for (int di = 0; di < 4; ++di)
            #pragma unroll
            for (int dj = 0; dj < 4; ++dj) {
                float v = 0.f;
                #pragma unroll
                for (int t = 0; t < 8; ++t) v += sAl[b][t] * mt[t][di * 4 + dj];
                wsW[(size_t)b * WELEM + (size_t)(i0 + tr * 4 + di) * 768 + j0 + tc * 4 + dj] =
                    f2bf(w0v[di * 4 + dj] + 2.0f * v);
            }
}

// ---------------------------------------------------------------------------
// Kernel 2: zero-halo-padded bf16 copy of x:  xp[b][c][58][58]
// ---------------------------------------------------------------------------
__global__ __launch_bounds__(256) void pad_x(
    const float* __restrict__ x, unsigned short* __restrict__ xp)
{
    int idx = blockIdx.x * 256 + threadIdx.x;
    int xx = idx % HP;
    int t1 = idx / HP;
    int yy = t1 % HP;
    int bc = t1 / HP;
    float v = 0.f;
    if (xx >= 1 && xx <= WW && yy >= 1 && yy <= HH)
        v = x[((size_t)bc * HH + (yy - 1)) * WW + (xx - 1)];
    xp[idx] = f2bf(v);
}

// ---------------------------------------------------------------------------
// Kernel 3: implicit-GEMM conv via MFMA.
// Tile: BM=128 (o) x BN=112 (spatial = 2 image rows), BK=32, 72 K-steps.
// A staged via global_load_lds width-16 into linear LDS with XOR granule
// swizzle (source pre-swizzled + same XOR on fragment read: g ^= (row>>1)&3).
// Grid: (28 nTiles, 2 mTiles, 32 samples), 256 threads.
// ---------------------------------------------------------------------------
template <bool PAD>
__global__ __launch_bounds__(256) void conv_mfma(
    const float* __restrict__ x,
    const unsigned short* __restrict__ xp,
    const unsigned short* __restrict__ wsW,
    float* __restrict__ out)
{
    __shared__ unsigned short AsmL[128 * 32];   // linear [row][granule], swizzled content
    __shared__ unsigned short Bsm[112][40];     // [n][kk], pitch 40

    const int nT = blockIdx.x;
    const int mT = blockIdx.y;
    const int b  = blockIdx.z;
    const int tid  = threadIdx.x;
    const int wv   = tid >> 6;
    const int lane = tid & 63;
    const int y0   = nT * 2;

    f32x4 acc[2][7];
    #pragma unroll
    for (int mf = 0; mf < 2; ++mf)
        #pragma unroll
        for (int nf = 0; nf < 7; ++nf)
            acc[mf][nf] = (f32x4){0.f, 0.f, 0.f, 0.f};

    const unsigned short* wBase = wsW + (size_t)b * WELEM + (size_t)(mT * 128) * KTOT;

    // A-staging: round r, thread -> physical granule p = r*256+tid.
    const int arow_lo = tid >> 2;   // row within 64-row half
    const int ag      = tid & 3;    // physical granule within row
    // B-staging mapping (unchanged)
    const int bkk = tid >> 3;
    const int bg  = tid & 7;

    for (int kt = 0; kt < 72; ++kt) {
        const int k0 = kt * 32;

        // ---- stage A: 2x global_load_lds (16B/lane), swizzled source ----
        #pragma unroll
        for (int r = 0; r < 2; ++r) {
            const int row  = r * 64 + arow_lo;
            const int gsrc = ag ^ ((row >> 1) & 3);
            const unsigned short* src = wBase + (size_t)row * KTOT + k0 + gsrc * 8;
            unsigned short* dst = &AsmL[(size_t)(r * 256 + wv * 64) * 8];  // wave-uniform
            __builtin_amdgcn_global_load_lds(
                (const __attribute__((address_space(1))) void*)src,
                (__attribute__((address_space(3))) void*)dst, 16, 0, 0);
        }

        // ---- stage B (im2col of x) ----
        {
            const int kidx = k0 + bkk;
            const int ci = kidx / 9;
            const int p  = kidx - ci * 9;
            const int dy = p / 3;
            const int dx = p - dy * 3;
            const int n0 = bg * 14;
            if (PAD) {
                const int yy = y0 + (bg >> 2) + dy;
                const int xb = (bg & 3) * 14 + dx;
                const unsigned short* src = xp + ((size_t)(b * CI + ci) * HP + yy) * HP + xb;
                #pragma unroll
                for (int e = 0; e < 14; ++e) Bsm[n0 + e][bkk] = src[e];
            } else {
                const int yb = y0 + (bg >> 2) + dy - 1;
                const bool yok = (yb >= 0) && (yb < HH);
                const float* src = x + ((size_t)(b * CI + ci) * HH + yb) * WW;
                #pragma unroll
                for (int e = 0; e < 14; ++e) {
                    int xc = (bg & 3) * 14 + e + dx - 1;
                    float v = (yok && xc >= 0 && xc < WW) ? src[xc] : 0.f;
                    Bsm[n0 + e][bkk] = f2bf(v);
                }
            }
        }
        __syncthreads();

        // ---- fragments + MFMA ----
        const int rsel = lane & 15;
        const int g0   = lane >> 4;
        short8 af[2], bfr[7];
        #pragma unroll
        for (int mf = 0; mf < 2; ++mf) {
            const int rowA = wv * 32 + mf * 16 + rsel;
            af[mf] = *(const short8*)&AsmL[rowA * 32 + ((g0 ^ ((rowA >> 1) & 3)) << 3)];
        }
        #pragma unroll
        for (int nf = 0; nf < 7; ++nf)
            bfr[nf] = *(const short8*)&Bsm[nf * 16 + rsel][g0 * 8];
        #pragma unroll
        for (int mf = 0; mf < 2; ++mf)
            #pragma unroll
            for (int nf = 0; nf < 7; ++nf)
                acc[mf][nf] = __builtin_amdgcn_mfma_f32_16x16x32_bf16(
                    af[mf], bfr[nf], acc[mf][nf], 0, 0, 0);
        __syncthreads();
    }

    // ---- epilogue: D[row=(l>>4)*4+r][col=l&15] ----
    const int colb = lane & 15;
    const int rowb = (lane >> 4) * 4;
    #pragma unroll
    for (int mf = 0; mf < 2; ++mf) {
        const int o = mT * 128 + wv * 32 + mf * 16 + rowb;
        #pragma unroll
        for (int nf = 0; nf < 7; ++nf) {
            const int s = nT * 112 + nf * 16 + colb;
            float* dst = out + ((size_t)(b * CO + o)) * SPAT + s;
            #pragma unroll
            for (int r = 0; r < 4; ++r)
                dst[(size_t)r * SPAT] = acc[mf][nf][r];
        }
    }
}

// ---------------------------------------------------------------------------
extern "C" void kernel_launch(void* const* d_in, const int* in_sizes, int n_in,
                              void* d_out, int out_size, void* d_ws, size_t ws_size,
                              hipStream_t stream)
{
    const float* x  = (const float*)d_in[0];
    const float* al = (const float*)d_in[1];
    const float* w0 = (const float*)d_in[2];
    const float* lA = (const float*)d_in[3];
    const float* lB = (const float*)d_in[4];
    float* out = (float*)d_out;

    const size_t sz_wsW = (size_t)NB * WELEM * 2;        // 37,748,736 B
    const size_t sz_M   = (size_t)8 * MELEM * 4;         // 18,874,368 B
    const size_t sz_xp  = (size_t)NB * CI * HP * HP * 2; // 55,115,776 B

    unsigned short* wsW  = (unsigned short*)d_ws;
    float*          Mst  = (float*)((char*)d_ws + sz_wsW);
    unsigned short* xpad = (unsigned short*)((char*)d_ws + sz_wsW + sz_M);

    const bool haveM   = ws_size >= sz_wsW + sz_M;
    const bool havePad = ws_size >= sz_wsW + sz_M + sz_xp;

    if (haveM) {
        mstack_gemm<<<dim3(144, 8), 256, 0, stream>>>(lA, lB, Mst);
        combine_weights<<<dim3(288, 4), 256, 0, stream>>>(al, w0, Mst, wsW);
    } else {
        synth_weights_fb<<<144, 256, 0, stream>>>(al, w0, lA, lB, wsW);
    }

    if (havePad) {
        pad_x<<<(int)(((size_t)NB * CI * HP * HP) / 256), 256, 0, stream>>>(x, xpad);
        conv_mfma<true><<<dim3(28, 2, 32), 256, 0, stream>>>(x, xpad, wsW, out);
    } else {
        conv_mfma<false><<<dim3(28, 2, 32), 256, 0, stream>>>(x, xpad, wsW, out);
    }
}